// Round 10
// baseline (6030.355 us; speedup 1.0000x reference)
//
#include <hip/hip_runtime.h>
#include <math.h>

// Problem constants
#define N_ROWS   131072      // 32*64*64 pixels
#define DIM      64          // embedding dim
#define KCODES   1024        // codebook entries
#define HWSZ     4096        // 64*64
#define CHW      262144      // 64*64*64 (per-batch NCHW stride)
#define OUT_ELEMS 8388608    // 32*64*64*64
#define BLOCK    384         // 6 waves; each lane owns 3 codes (192 w-regs)
#define PXB      512         // pixels per block
#define NBLOCKS  (N_ROWS / PXB)      // 256 -> 1 block/CU
#define CH_PAIRS 128                 // pixel-pairs per LDS chunk (256 px)
#define XSTR     132                 // floats per pair row (66 f2, pad for b128 align)

typedef float v2f __attribute__((ext_vector_type(2)));

// packed fma over the 2 pixels of a pair; each component is an independent
// exact IEEE fp32 fma chain -> bit-identical per pixel (r8-proven path).
__device__ __forceinline__ v2f fma2(v2f a, float b, v2f c) {
#if __has_builtin(__builtin_elementwise_fma)
    v2f bb = {b, b};
    return __builtin_elementwise_fma(a, bb, c);
#else
    v2f r;
    r[0] = __builtin_fmaf(a[0], b, c[0]);
    r[1] = __builtin_fmaf(a[1], b, c[1]);
    return r;
#endif
}

// ---------------------------------------------------------------------------
// numpy pairwise sum of squares, n=64 (8-accumulator block, scalar order).
// ---------------------------------------------------------------------------
__device__ __forceinline__ float np_sumsq64(const float* v) {
#pragma clang fp contract(off)
    float r[8];
#pragma unroll
    for (int j = 0; j < 8; ++j) r[j] = v[j] * v[j];
#pragma unroll
    for (int i = 8; i < 64; i += 8) {
#pragma unroll
        for (int j = 0; j < 8; ++j) {
            float p = v[i + j] * v[i + j];
            r[j] = r[j] + p;
        }
    }
    float s01 = r[0] + r[1];
    float s23 = r[2] + r[3];
    float s45 = r[4] + r[5];
    float s67 = r[6] + r[7];
    return (s01 + s23) + (s45 + s67);
}

// Same value sequence reading stride-2 floats (x stored as f2 pairs in LDS).
__device__ __forceinline__ float np_sumsq64_str2(const float* v) {
#pragma clang fp contract(off)
    float r[8];
#pragma unroll
    for (int j = 0; j < 8; ++j) {
        const float t = v[2 * j];
        r[j] = t * t;
    }
#pragma unroll
    for (int i = 8; i < 64; i += 8) {
#pragma unroll
        for (int j = 0; j < 8; ++j) {
            const float t = v[2 * (i + j)];
            const float p = t * t;
            r[j] = r[j] + p;
        }
    }
    float s01 = r[0] + r[1];
    float s23 = r[2] + r[3];
    float s45 = r[4] + r[5];
    float s67 = r[6] + r[7];
    return (s01 + s23) + (s45 + s67);
}

// ---------------------------------------------------------------------------
// Kernel 0: per-code ||w_k||^2 (numpy-pairwise) -> ws[0..1023]
// ---------------------------------------------------------------------------
__global__ __launch_bounds__(256) void vq_wsum(const float* __restrict__ w,
                                               float* __restrict__ wsum) {
    int k = blockIdx.x * blockDim.x + threadIdx.x;   // grid = 4*256 = 1024
    const float* wr = w + k * DIM;
    float wv[DIM];
#pragma unroll
    for (int d = 0; d < DIM; ++d) wv[d] = wr[d];
    wsum[k] = np_sumsq64(wv);
}

// ---------------------------------------------------------------------------
// argmin key: (monotone-u32(dk) << 32) | code.  u64-min == "first index of
// min over exact fp32 dk" (monotone map preserves IEEE order incl. negatives;
// ties in dk bits resolve to the smaller code index).  Order-invariant.
// ---------------------------------------------------------------------------
__device__ __forceinline__ unsigned long long dist_key(float dk, int k) {
    unsigned int b = __float_as_uint(dk);
    unsigned int m = 0x80000000u | (unsigned int)((int)b >> 31);
    return ((unsigned long long)(b ^ m) << 32) | (unsigned int)k;
}

// 16-lane-row min-reduction stage via DPP row_shr (pure VALU, no LDS pipe).
// After shifts 1,2,4,8: lanes 15/31/47/63 hold their row's min.
#define DPP_MIN_STAGE(key, CTRL)                                               \
    {                                                                          \
        unsigned int _lo = (unsigned int)(key);                                \
        unsigned int _hi = (unsigned int)((key) >> 32);                        \
        unsigned int _ol = (unsigned int)__builtin_amdgcn_update_dpp(          \
            -1, (int)_lo, (CTRL), 0xF, 0xF, false);                            \
        unsigned int _oh = (unsigned int)__builtin_amdgcn_update_dpp(          \
            -1, (int)_hi, (CTRL), 0xF, 0xF, false);                            \
        unsigned long long _o =                                                \
            ((unsigned long long)_oh << 32) | (unsigned long long)_ol;         \
        key = (_o < (key)) ? _o : (key);                                       \
    }

// ---------------------------------------------------------------------------
// Kernel 1: main VQ — CODES-IN-REGISTERS / x-broadcast (scheme flip).
//   Fill law (r3/r6/r8/r9): weight delivery = ~10cyc per wave-wide 16B/lane
//   register fill; scheme A's reuse (pixels/thread) is capped at 2 by the
//   256-VGPR file (r9: P=4 spilled catastrophically). Flip the rank-1
//   structure: each lane holds THREE codes' weights statically in 192 VGPRs
//   (filled ONCE), and the x rows stream as LDS broadcasts, amortized over
//   3 codes/lane. Fills/CU: 512px * 33 * 6 waves = 50.7K ~= 507K cyc ~211us
//   vs r3's 640K wall.
//   - 6 waves * 64 lanes * 3 codes = 1152 slots >= 1024 (k = tid + 384j,
//     clamped; duplicates of code 1023 are bit-identical -> u64-min dedups).
//   - per pair: 192 pk-fma (2 px/op) + lane-local min3 + 4-stage DPP row
//     reduce -> 4 candidates/wave -> 48KB LDS cand array; final 24-way scan.
//   - x chunked 128 pairs (67.6KB LDS), staged coalesced; a[] precomputed
//     per pixel with the exact np 8-acc pattern.
//   Numerics BIT-IDENTICAL per (pixel, code):
//     a  = np_sumsq64(x);  c = sequential fmaf chain d=0..63 (per component)
//     dk = fl( fl(a+b_k) - 2*c );  argmin == ascending strict-< (u64 keys)
// ---------------------------------------------------------------------------
__global__ __launch_bounds__(384, 2) void vq_main(const float* __restrict__ inp,
                                                  const float* __restrict__ weight,
                                                  const float* __restrict__ wsum,
                                                  float* __restrict__ out,
                                                  float* __restrict__ idx_out,
                                                  float* __restrict__ block_loss) {
    __shared__ float xls[CH_PAIRS * XSTR + 8];            // 67.6 KB x chunk
    __shared__ float als[2 * CH_PAIRS];                   // per-pixel a
    __shared__ unsigned long long cand[6][CH_PAIRS][2][4]; // 48 KB candidates
    __shared__ float red[BLOCK / 64];

    const int tid  = threadIdx.x;
    const int lane = tid & 63;
    const int wvid = tid >> 6;                 // 0..5
    const int nbase = blockIdx.x * PXB;
    const int b    = nbase >> 12;              // constant per block (512|4096)
    const int hw0  = nbase & 4095;

    // ---- per-lane codes: k = tid + 384j (clamped duplicates harmless) ----
    const int k0 = tid;
    const int k1 = tid + 384;
    int k2 = tid + 768; if (k2 > 1023) k2 = 1023;

    // ---- load the 3 code rows into 192 static VGPRs ----
    float w0[DIM], w1[DIM], w2[DIM];
    {
        const float4* wv = (const float4*)weight;
#pragma unroll
        for (int j = 0; j < 16; ++j) {
            const float4 t0 = wv[k0 * 16 + j];
            w0[4 * j] = t0.x; w0[4 * j + 1] = t0.y; w0[4 * j + 2] = t0.z; w0[4 * j + 3] = t0.w;
            const float4 t1 = wv[k1 * 16 + j];
            w1[4 * j] = t1.x; w1[4 * j + 1] = t1.y; w1[4 * j + 2] = t1.z; w1[4 * j + 3] = t1.w;
            const float4 t2 = wv[k2 * 16 + j];
            w2[4 * j] = t2.x; w2[4 * j + 1] = t2.y; w2[4 * j + 2] = t2.z; w2[4 * j + 3] = t2.w;
        }
    }
    const float ws0 = wsum[k0];
    const float ws1 = wsum[k1];
    const float ws2 = wsum[k2];

    float lsacc = 0.f;

    for (int ch = 0; ch < 2; ++ch) {
        __syncthreads();   // protect previous chunk's x/cand readers

        // ---- stage x chunk: 256 px * 64 d, coalesced f2, pair-major LDS ----
        {
            const float* src = inp + (size_t)b * CHW + hw0 + ch * 256;
            for (int i = tid; i < CH_PAIRS * DIM; i += BLOCK) {
                const int d  = i >> 7;          // 0..63
                const int pr = i & 127;         // pair
                const float2 v = *(const float2*)(src + (size_t)d * HWSZ + pr * 2);
                *(float2*)(xls + pr * XSTR + d * 2) = v;
            }
        }
        __syncthreads();

        // ---- a-pass: exact np_sumsq64 per pixel (wave-uniform component) ----
        if (tid < 256) {
            const int comp = tid >> 7;          // 0 for waves 0-1, 1 for 2-3
            const int pr   = tid & 127;
            const float a  = np_sumsq64_str2(xls + pr * XSTR + comp);
            als[pr * 2 + comp] = a;
        }
        __syncthreads();

        // ---- sweep: every wave runs all 128 pairs against its 3 codes ----
#pragma unroll 1
        for (int p = 0; p < CH_PAIRS; ++p) {
            const float*  xr  = xls + p * XSTR;
            const float4* xr4 = (const float4*)xr;
            const float2  a2  = *(const float2*)(als + p * 2);   // broadcast

            v2f c0 = {0.f, 0.f}, c1 = {0.f, 0.f}, c2 = {0.f, 0.f};

            // stream 16 chunks of 4 dims with A/B prefetch (compile-time idx)
            float4 Xa = xr4[0], Xb = xr4[1];
            float4 Ya, Yb;
#pragma unroll
            for (int cc = 0; cc < 16; cc += 2) {
                const int nA = cc + 1;
                const int nB = (cc + 2) & 15;
                Ya = xr4[nA * 2]; Yb = xr4[nA * 2 + 1];   // prefetch odd chunk
#pragma unroll
                for (int e = 0; e < 2; ++e) {             // dims 4cc+2e{,+1}
                    const float4 u = e ? Xb : Xa;
                    const int d = 4 * cc + 2 * e;
                    v2f xv0; xv0[0] = u.x; xv0[1] = u.y;
                    c0 = fma2(xv0, w0[d], c0); c1 = fma2(xv0, w1[d], c1); c2 = fma2(xv0, w2[d], c2);
                    v2f xv1; xv1[0] = u.z; xv1[1] = u.w;
                    c0 = fma2(xv1, w0[d + 1], c0); c1 = fma2(xv1, w1[d + 1], c1); c2 = fma2(xv1, w2[d + 1], c2);
                }
                Xa = xr4[nB * 2]; Xb = xr4[nB * 2 + 1];   // prefetch next even
#pragma unroll
                for (int e = 0; e < 2; ++e) {
                    const float4 u = e ? Yb : Ya;
                    const int d = 4 * (cc + 1) + 2 * e;
                    v2f xv0; xv0[0] = u.x; xv0[1] = u.y;
                    c0 = fma2(xv0, w0[d], c0); c1 = fma2(xv0, w1[d], c1); c2 = fma2(xv0, w2[d], c2);
                    v2f xv1; xv1[0] = u.z; xv1[1] = u.w;
                    c0 = fma2(xv1, w0[d + 1], c0); c1 = fma2(xv1, w1[d + 1], c1); c2 = fma2(xv1, w2[d + 1], c2);
                }
            }

            // dk per (code, pixel) — exact chain tail
            float d0p, d0q, d1p, d1q, d2p, d2q;
            {
#pragma clang fp contract(off)
                const float s0p = a2.x + ws0; d0p = s0p - 2.0f * c0[0];
                const float s0q = a2.y + ws0; d0q = s0q - 2.0f * c0[1];
                const float s1p = a2.x + ws1; d1p = s1p - 2.0f * c1[0];
                const float s1q = a2.y + ws1; d1q = s1q - 2.0f * c1[1];
                const float s2p = a2.x + ws2; d2p = s2p - 2.0f * c2[0];
                const float s2q = a2.y + ws2; d2q = s2q - 2.0f * c2[1];
            }
            // lane-local min over the 3 codes (u64 keys)
            unsigned long long kp = dist_key(d0p, k0);
            {
                unsigned long long t = dist_key(d1p, k1); kp = t < kp ? t : kp;
                t = dist_key(d2p, k2); kp = t < kp ? t : kp;
            }
            unsigned long long kq = dist_key(d0q, k0);
            {
                unsigned long long t = dist_key(d1q, k1); kq = t < kq ? t : kq;
                t = dist_key(d2q, k2); kq = t < kq ? t : kq;
            }
            // 4-stage DPP row reduction: lanes 15/31/47/63 hold row-mins
            DPP_MIN_STAGE(kp, 0x111); DPP_MIN_STAGE(kq, 0x111);
            DPP_MIN_STAGE(kp, 0x112); DPP_MIN_STAGE(kq, 0x112);
            DPP_MIN_STAGE(kp, 0x114); DPP_MIN_STAGE(kq, 0x114);
            DPP_MIN_STAGE(kp, 0x118); DPP_MIN_STAGE(kq, 0x118);
            if ((lane & 15) == 15) {
                cand[wvid][p][0][lane >> 4] = kp;
                cand[wvid][p][1][lane >> 4] = kq;
            }
        }
        __syncthreads();

        // ---- final reduce + epilogue: one thread per pixel of the chunk ----
        if (tid < 256) {
            const int comp = tid >> 7;          // wave-uniform
            const int pr   = tid & 127;
            unsigned long long best = cand[0][pr][comp][0];
#pragma unroll
            for (int w = 0; w < 6; ++w)
#pragma unroll
                for (int r = 0; r < 4; ++r) {
                    const unsigned long long t = cand[w][pr][comp][r];
                    best = t < best ? t : best;
                }
            const int bk  = (int)(unsigned int)(best & 0xFFFFFFFFull);
            const int pxl = pr * 2 + comp;
            const int n   = nbase + ch * 256 + pxl;
            const int hw  = hw0 + ch * 256 + pxl;

            const float* wb = weight + bk * DIM;      // per-lane gather, L2-hot
            float* ob = out + (size_t)b * CHW + hw;
            const float* xr = xls + pr * XSTR + comp; // x[d] at xr[2d]
            float ls = 0.f;
#pragma unroll
            for (int d = 0; d < DIM; ++d) {
                const float wv = wb[d];
                ob[(size_t)d * HWSZ] = wv;
                const float df = wv - xr[2 * d];
                ls = fmaf(df, df, ls);
            }
            lsacc += ls;
            idx_out[n] = (float)bk;
        }
    }

    // ---- block reduction of loss partial (6 waves) ----
    float ls = lsacc;
#pragma unroll
    for (int off = 32; off > 0; off >>= 1) ls += __shfl_down(ls, off, 64);
    if (lane == 0) red[wvid] = ls;
    __syncthreads();
    if (tid == 0) {
        float s = 0.f;
#pragma unroll
        for (int w = 0; w < BLOCK / 64; ++w) s += red[w];
        block_loss[blockIdx.x] = s;
    }
}

// ---------------------------------------------------------------------------
// Kernel 2: reduce 256 block partials -> loss scalar
//   loss = q + 0.25*e = 1.25 * mean((quantized - x)^2)
// ---------------------------------------------------------------------------
__global__ __launch_bounds__(256) void vq_loss_reduce(const float* __restrict__ bl,
                                                      float* __restrict__ loss_out) {
    double s = 0.0;
    for (int i = threadIdx.x; i < NBLOCKS; i += 256) s += (double)bl[i];
    __shared__ double red[4];
#pragma unroll
    for (int off = 32; off > 0; off >>= 1) s += __shfl_down(s, off, 64);
    const int lane = threadIdx.x & 63;
    const int wid  = threadIdx.x >> 6;
    if (lane == 0) red[wid] = s;
    __syncthreads();
    if (threadIdx.x == 0) {
        const double total = (red[0] + red[1]) + (red[2] + red[3]);
        loss_out[0] = (float)(1.25 * total / (double)OUT_ELEMS);
    }
}

// ---------------------------------------------------------------------------
extern "C" void kernel_launch(void* const* d_in, const int* in_sizes, int n_in,
                              void* d_out, int out_size, void* d_ws, size_t ws_size,
                              hipStream_t stream) {
    const float* inp    = (const float*)d_in[0];   // [32,64,64,64] NCHW fp32
    const float* weight = (const float*)d_in[1];   // [1024,64] fp32

    float* out_q    = (float*)d_out;                         // 8388608 elems
    float* out_loss = (float*)d_out + OUT_ELEMS;             // 1 elem
    float* out_idx  = (float*)d_out + OUT_ELEMS + 1;         // 131072 elems

    float* wsum       = (float*)d_ws;                        // 1024 floats
    float* block_loss = (float*)d_ws + KCODES;               // 256 floats

    vq_wsum<<<KCODES / 256, 256, 0, stream>>>(weight, wsum);
    vq_main<<<NBLOCKS, BLOCK, 0, stream>>>(inp, weight, wsum,
                                           out_q, out_idx, block_loss);
    vq_loss_reduce<<<1, 256, 0, stream>>>(block_loss, out_loss);
}

// Round 11
// 473.282 us; speedup vs baseline: 12.7416x; 12.7416x over previous
//
#include <hip/hip_runtime.h>
#include <math.h>
#include <stdint.h>

// Problem constants
#define N_ROWS   131072      // 32*64*64 pixels
#define DIM      64          // embedding dim
#define KCODES   1024        // codebook entries
#define HWSZ     4096        // 64*64
#define CHW      262144      // 64*64*64 (per-batch NCHW stride)
#define OUT_ELEMS 8388608    // 32*64*64*64
#define BLOCK    256         // 4 waves; each wave owns 16 pixels
#define PXB      64          // pixels per block
#define NBLOCKS  (N_ROWS / PXB)   // 2048 blocks -> ~8/CU
#define XPAD     68          // xstage row stride (floats), +4 pad vs 64

typedef float f32x4 __attribute__((ext_vector_type(4)));
typedef short s16x8 __attribute__((ext_vector_type(8)));

// ---------------------------------------------------------------------------
// numpy pairwise sum of squares, n=64 (8-accumulator block, scalar order).
// Bit-exact np.sum(v**2, axis=-1); contract(off) keeps mul/add separate.
// ---------------------------------------------------------------------------
__device__ __forceinline__ float np_sumsq64(const float* v) {
#pragma clang fp contract(off)
    float r[8];
#pragma unroll
    for (int j = 0; j < 8; ++j) r[j] = v[j] * v[j];
#pragma unroll
    for (int i = 8; i < 64; i += 8) {
#pragma unroll
        for (int j = 0; j < 8; ++j) {
            float p = v[i + j] * v[i + j];
            r[j] = r[j] + p;
        }
    }
    float s01 = r[0] + r[1];
    float s23 = r[2] + r[3];
    float s45 = r[4] + r[5];
    float s67 = r[6] + r[7];
    return (s01 + s23) + (s45 + s67);
}

// bf16 round-to-nearest-even (no NaN/Inf in this data)
__device__ __forceinline__ unsigned bf16_rne(float f) {
    unsigned u = __float_as_uint(f);
    return (u + 0x7fffu + ((u >> 16) & 1u)) >> 16;
}

// order-preserving u32 map of fp32; key = (mono<<32)|code  =>
// u64-min == "first index of min" (ties in bits -> smaller code).
__device__ __forceinline__ unsigned long long mono_key(float f, int k) {
    unsigned u = __float_as_uint(f);
    unsigned m = (u & 0x80000000u) ? ~u : (u | 0x80000000u);
    return ((unsigned long long)m << 32) | (unsigned)k;
}
__device__ __forceinline__ float unmono(unsigned long long key) {
    unsigned m = (unsigned)(key >> 32);
    unsigned u = (m & 0x80000000u) ? (m ^ 0x80000000u) : ~m;
    return __uint_as_float(u);
}

__device__ __forceinline__ unsigned long long shflx64(unsigned long long v, int mask) {
    unsigned lo = (unsigned)__shfl_xor((int)(unsigned)v, mask, 64);
    unsigned hi = (unsigned)__shfl_xor((int)(unsigned)(v >> 32), mask, 64);
    return ((unsigned long long)hi << 32) | lo;
}

// exact reference chain: a = np_sumsq64(x); c = sequential fmaf d=0..63;
// dk = fl( fl(a+b_k) - 2*c )  — BIT-IDENTICAL to all passing rounds.
__device__ __forceinline__ float exact_dk(const float* __restrict__ xs,
                                          const float* __restrict__ wr,
                                          float a, float bsw) {
    float c = 0.f;
#pragma unroll
    for (int d = 0; d < DIM; ++d) c = __builtin_fmaf(xs[d], wr[d], c);
    float dk;
    {
#pragma clang fp contract(off)
        const float s = a + bsw;
        dk = s - 2.0f * c;
    }
    return dk;
}

// ---------------------------------------------------------------------------
// Kernel 0: per-code ||w_k||^2 (exact, as before) + MFMA fragment build.
//   W' = -2w split to bf16 (wh = rne(W'), wl = rne(W'-wh)), stored in
//   FRAGMENT ORDER so sweep loads are coalesced dwordx4:
//   A-frag mapping (16x16x32): lane l -> row (l&15) = code-in-tile,
//   kslots 8*(l>>4)+j (j=0..7) -> dim = 32*chunk + 8*(l>>4) + j.
//   Blocks of 1024B: [tile t][wh_c0, wl_c0, wh_c1, wl_c1] at t*4096.
// ---------------------------------------------------------------------------
__global__ __launch_bounds__(256) void vq_prep(const float* __restrict__ w,
                                               float* __restrict__ wsum,
                                               unsigned short* __restrict__ frags) {
    const int k = blockIdx.x * 256 + threadIdx.x;   // grid 4*256 = 1024
    const float* wr = w + k * DIM;
    float wv[DIM];
#pragma unroll
    for (int d = 0; d < DIM; ++d) wv[d] = wr[d];
    wsum[k] = np_sumsq64(wv);

    const int t = k >> 4, r = k & 15;
#pragma unroll
    for (int d = 0; d < DIM; ++d) {
        const float wp = -2.0f * wv[d];
        const unsigned hb = bf16_rne(wp);
        const float hf = __uint_as_float(hb << 16);
        const unsigned lb = bf16_rne(wp - hf);
        const int c = d >> 5, dd = d & 31, g = dd >> 3, j = dd & 7;
        const int fb = 4 * t + 2 * c;                  // wh block; +1 = wl
        const int base = fb * 512 + (r + 16 * g) * 8 + j;
        frags[base] = (unsigned short)hb;
        frags[base + 512] = (unsigned short)lb;
    }
}

// ---------------------------------------------------------------------------
// Kernel 1: main VQ — MFMA prefilter + certified exact argmin.
//   Fill-law escape: 16x16x32 bf16 MFMA gives 128 MAC/lane per 16B/lane of
//   operand fill (VALU schemes: 8). 3-pass split-bf16 (xh*wh + xh*wl + xl*wh
//   with W'=-2w) gives dk_hat within ~ulp(64)+2e-6 of the exact dk.
//   Per pixel: track (min1,min2) u64 keys; certify if v2-v1 > band; validate
//   every certified winner with ONE exact chain (any MFMA layout error =>
//   mismatch => fallback => still correct, just slow). Uncertified pixels:
//   cooperative exact sweep (256 threads x 4 codes, bit-exact chain).
//   No LDS and no barriers in the MFMA sweep; W-frags stream coalesced from
//   L2 (256 KB resident); x staged once in LDS per block.
// ---------------------------------------------------------------------------
__global__ __launch_bounds__(256) void vq_main(const float* __restrict__ inp,
                                               const float* __restrict__ weight,
                                               const float* __restrict__ wsum,
                                               const unsigned short* __restrict__ frags,
                                               float* __restrict__ out,
                                               float* __restrict__ idx_out,
                                               float* __restrict__ block_loss) {
    __shared__ float xstage[PXB * XPAD];     // 17.4 KB x tile (row-major px)
    __shared__ float als[PXB];               // per-pixel a (exact np chain)
    __shared__ float v1s[PXB];
    __shared__ int   finalidx[PXB];
    __shared__ int   needchk[PXB];
    __shared__ int   flags[PXB];
    __shared__ int   nflag;
    __shared__ unsigned long long wred[4];

    const int tid  = threadIdx.x;
    const int lane = tid & 63;
    const int wv   = tid >> 6;               // wave 0..3
    const int nbase = blockIdx.x * PXB;
    const int b    = nbase >> 12;            // constant per block (64 | 4096)
    const int hw0  = nbase & 4095;

    if (tid == 0) nflag = 0;
    if (tid < PXB) needchk[tid] = 0;

    // ---- stage x tile: 64 px * 64 d, coalesced; xstage[px][d] ----
    {
        const float* src = inp + (size_t)b * CHW + hw0;
#pragma unroll
        for (int it = 0; it < (PXB * DIM) / BLOCK; ++it) {
            const int i = tid + BLOCK * it;
            const int px = i & 63;
            const int d  = i >> 6;
            xstage[px * XPAD + d] = src[(size_t)d * HWSZ + px];
        }
    }
    __syncthreads();
    if (tid < PXB) als[tid] = np_sumsq64(&xstage[tid * XPAD]);
    __syncthreads();

    // ---- per-lane B-fragments: px = 16*wave + (lane&15), splits xh/xl ----
    const int pxl = (wv << 4) | (lane & 15);
    const int g   = lane >> 4;
    const float a_px = als[pxl];

    s16x8 xh0, xh1, xl0, xl1;
    {
        const float* xr = &xstage[pxl * XPAD];
#pragma unroll
        for (int j = 0; j < 8; ++j) {
            const float f0 = xr[8 * g + j];            // chunk 0: dims 8g+j
            const unsigned h0 = bf16_rne(f0);
            xh0[j] = (short)h0;
            xl0[j] = (short)bf16_rne(f0 - __uint_as_float(h0 << 16));
            const float f1 = xr[32 + 8 * g + j];       // chunk 1: dims 32+8g+j
            const unsigned h1 = bf16_rne(f1);
            xh1[j] = (short)h1;
            xl1[j] = (short)bf16_rne(f1 - __uint_as_float(h1 << 16));
        }
    }

    // ---- MFMA sweep over 64 code-tiles; track min1/min2 per lane ----
    unsigned long long m1 = ~0ull, m2 = ~0ull;
    const char* fbytes = (const char*)frags;

#pragma unroll 1
    for (int t = 0; t < 64; ++t) {
        const s16x8* fp = (const s16x8*)(fbytes + (size_t)t * 4096);
        const s16x8 whc0 = fp[lane];
        const s16x8 wlc0 = fp[64 + lane];
        const s16x8 whc1 = fp[128 + lane];
        const s16x8 wlc1 = fp[192 + lane];

        f32x4 acc = {0.f, 0.f, 0.f, 0.f};
        acc = __builtin_amdgcn_mfma_f32_16x16x32_bf16(whc0, xh0, acc, 0, 0, 0);
        acc = __builtin_amdgcn_mfma_f32_16x16x32_bf16(whc1, xh1, acc, 0, 0, 0);
        acc = __builtin_amdgcn_mfma_f32_16x16x32_bf16(wlc0, xh0, acc, 0, 0, 0);
        acc = __builtin_amdgcn_mfma_f32_16x16x32_bf16(wlc1, xh1, acc, 0, 0, 0);
        acc = __builtin_amdgcn_mfma_f32_16x16x32_bf16(whc0, xl0, acc, 0, 0, 0);
        acc = __builtin_amdgcn_mfma_f32_16x16x32_bf16(whc1, xl1, acc, 0, 0, 0);

        // D row = 4g+reg -> code = t*16 + 4g + reg (4 consecutive codes)
        const float4 wsv = *(const float4*)(wsum + t * 16 + 4 * g);
#pragma unroll
        for (int reg = 0; reg < 4; ++reg) {
            const float bsw = (reg == 0) ? wsv.x : (reg == 1) ? wsv.y
                             : (reg == 2) ? wsv.z : wsv.w;
            const float S = a_px + bsw;         // fl(a+b)
            const float v = S + acc[reg];       // fl(S + C), C ~ -2c
            const unsigned long long key = mono_key(v, t * 16 + 4 * g + reg);
            if (key < m1) { m2 = m1; m1 = key; }
            else if (key < m2) { m2 = key; }
        }
    }

    // ---- dup-free XOR-tree merge across the 4 lane-groups of each px ----
#pragma unroll
    for (int mk = 16; mk <= 32; mk <<= 1) {
        const unsigned long long q1 = shflx64(m1, mk);
        const unsigned long long q2 = shflx64(m2, mk);
        if (q1 < m1) { m2 = (m1 < q2) ? m1 : q2; m1 = q1; }
        else         { m2 = (m2 < q1) ? m2 : q1; }
    }

    // ---- certification (lanes 0..15 of each wave own one px) ----
    if (g == 0) {
        const float v1 = unmono(m1);
        const float v2 = unmono(m2);
        const float u_p = fabsf(v1) * 2.4e-7f;
        const float band = 3.0f * u_p + sqrtf(a_px) * 1e-5f + 4e-6f;
        const int k1 = (int)(unsigned)(m1 & 0xffffffffull);
        if (v2 - v1 > band) {
            finalidx[pxl] = k1;
            v1s[pxl] = v1;
            needchk[pxl] = 1;
        } else {
            const int p = atomicAdd(&nflag, 1);
            flags[p] = pxl;
        }
    }
    __syncthreads();

    // ---- validate certified winners with ONE exact chain each ----
    if (tid < PXB && needchk[tid]) {
        const int px = tid;
        const int k1 = finalidx[px];
        const float dk = exact_dk(&xstage[px * XPAD], weight + (size_t)k1 * DIM,
                                  als[px], wsum[k1]);
        const float v1 = v1s[px];
        const float u_p = fabsf(v1) * 2.4e-7f;
        const float vtol = 4.0f * u_p + sqrtf(als[px]) * 1e-5f + 4e-6f;
        if (fabsf(dk - v1) > vtol) {
            const int p = atomicAdd(&nflag, 1);
            flags[p] = px;
        }
    }
    __syncthreads();

    // ---- cooperative exact fallback (bit-exact, first-index-of-min) ----
    const int nf = nflag;
    for (int i = 0; i < nf; ++i) {
        const int px = flags[i];
        const float axp = als[px];
        const float* xs = &xstage[px * XPAD];
        unsigned long long mk = ~0ull;
#pragma unroll 1
        for (int kk = tid; kk < KCODES; kk += BLOCK) {
            const float dk = exact_dk(xs, weight + (size_t)kk * DIM, axp, wsum[kk]);
            const unsigned long long key = mono_key(dk, kk);
            if (key < mk) mk = key;
        }
#pragma unroll
        for (int o = 32; o > 0; o >>= 1) {
            const unsigned long long q = shflx64(mk, o);
            if (q < mk) mk = q;
        }
        if (lane == 0) wred[wv] = mk;
        __syncthreads();
        if (tid == 0) {
            unsigned long long m = wred[0];
            if (wred[1] < m) m = wred[1];
            if (wred[2] < m) m = wred[2];
            if (wred[3] < m) m = wred[3];
            finalidx[px] = (int)(unsigned)(m & 0xffffffffull);
        }
        __syncthreads();
    }

    // ---- epilogue: gather winning rows, write out (coalesced), loss ----
    float ls = 0.f;
    if (tid < PXB) {
        const int px = tid;
        const int bk = finalidx[px];
        const float* wb = weight + (size_t)bk * DIM;   // L2-hot gather
        float* ob = out + (size_t)b * CHW + hw0 + px;
        const float* xs = &xstage[px * XPAD];
#pragma unroll
        for (int d = 0; d < DIM; ++d) {
            const float wvv = wb[d];
            ob[(size_t)d * HWSZ] = wvv;
            const float df = wvv - xs[d];
            ls = fmaf(df, df, ls);
        }
        idx_out[nbase + px] = (float)bk;
    }
    // loss partials live entirely in wave 0 (tid 0..63)
    if (wv == 0) {
#pragma unroll
        for (int off = 32; off > 0; off >>= 1) ls += __shfl_down(ls, off, 64);
        if (lane == 0) block_loss[blockIdx.x] = ls;
    }
}

// ---------------------------------------------------------------------------
// Kernel 2: reduce 2048 block partials -> loss scalar
//   loss = q + 0.25*e = 1.25 * mean((quantized - x)^2)
// ---------------------------------------------------------------------------
__global__ __launch_bounds__(256) void vq_loss_reduce(const float* __restrict__ bl,
                                                      float* __restrict__ loss_out) {
    double s = 0.0;
    for (int i = threadIdx.x; i < NBLOCKS; i += 256) s += (double)bl[i];
    __shared__ double red[4];
#pragma unroll
    for (int off = 32; off > 0; off >>= 1) s += __shfl_down(s, off, 64);
    const int lane = threadIdx.x & 63;
    const int wid  = threadIdx.x >> 6;
    if (lane == 0) red[wid] = s;
    __syncthreads();
    if (threadIdx.x == 0) {
        const double total = (red[0] + red[1]) + (red[2] + red[3]);
        loss_out[0] = (float)(1.25 * total / (double)OUT_ELEMS);
    }
}

// ---------------------------------------------------------------------------
extern "C" void kernel_launch(void* const* d_in, const int* in_sizes, int n_in,
                              void* d_out, int out_size, void* d_ws, size_t ws_size,
                              hipStream_t stream) {
    const float* inp    = (const float*)d_in[0];   // [32,64,64,64] NCHW fp32
    const float* weight = (const float*)d_in[1];   // [1024,64] fp32

    float* out_q    = (float*)d_out;                         // 8388608 elems
    float* out_loss = (float*)d_out + OUT_ELEMS;             // 1 elem
    float* out_idx  = (float*)d_out + OUT_ELEMS + 1;         // 131072 elems

    // workspace: wsum[1024] f32 | frags 256 KB (bf16 splits, frag order) |
    //            block_loss[2048] f32   (total ~274 KB)
    float* wsum = (float*)d_ws;
    unsigned short* frags = (unsigned short*)((float*)d_ws + KCODES);
    float* block_loss = (float*)d_ws + KCODES + 65536;

    vq_prep<<<KCODES / 256, 256, 0, stream>>>(weight, wsum, frags);
    vq_main<<<NBLOCKS, BLOCK, 0, stream>>>(inp, weight, wsum, frags,
                                           out_q, out_idx, block_loss);
    vq_loss_reduce<<<1, 256, 0, stream>>>(block_loss, out_loss);
}